// Round 3
// baseline (226.865 us; speedup 1.0000x reference)
//
#include <hip/hip_runtime.h>

// B=8, H=8, L=2048, D=64, num_delays=16
static constexpr int LSEQ = 2048;
static constexpr int NB   = 8;
static constexpr int NH   = 8;
static constexpr int ND   = 64;
static constexpr int NDEL = 16;

// ws layout:
//   P     : float2[64 part][8 b][2048]  at 0        (8 MiB)  per-block partial spectra
//   S     : float2[8][2048]             at 8388608  (128 KiB) reduced spectrum (bit-rev order)
//   w     : float [8][16]               at 8519680
//   delay : int   [8][16]               at 8520192
static constexpr size_t WS_P_OFF     = 0;
static constexpr size_t WS_S_OFF     = 8388608;
static constexpr size_t WS_W_OFF     = 8519680;
static constexpr size_t WS_DELAY_OFF = 8520192;

// float2-space bank swizzle: folds bits 4..7 into bits 0..3. Hand-checked to
// give minimum LDS bank cycles for stage strides 512/128/32/8, the radix-8
// tail (aligned-8 permuted blocks), and consecutive access.
__device__ __forceinline__ int SW2(int j) { return j ^ ((j >> 4) & 15); }

// ---------------------------------------------------------------------------
// Kernel A: block = (b,h,grp) handles 8 channels in two 4-channel rounds.
// z = q + i*k packed FFT (radix-4 x4 + radix-8 tail, LDS twiddle tables),
// product Q*conj(K) accumulated in REGISTERS across rounds, one coalesced
// partial-spectrum store per block (bit-reversed order). NO atomics.
// ---------------------------------------------------------------------------
__global__ __launch_bounds__(256) void fft_corr(const float* __restrict__ q,
                                                const float* __restrict__ k,
                                                float2* __restrict__ P) {
    __shared__ float2 z[4][LSEQ];   // 64 KiB, swizzled
    __shared__ float2 tw[680];      // stage twiddles: 512 | 128 | 32 | 8

    const int tid = threadIdx.x;
    const int bi  = blockIdx.x;         // 512 = 8 xcd * 8 bh * 8 grp
    const int xcd = bi & 7;
    const int sl  = bi >> 3;            // 0..63
    const int bh  = xcd * 8 + (sl >> 3);
    const int grp = sl & 7;
    const int b   = bh >> 3;
    const int h   = bh & 7;
    const size_t base = (size_t)bh * LSEQ * ND + (size_t)(grp * 8);

    // twiddle tables (exp(-2*pi*i*idx/M))
    for (int i = tid; i < 680; i += 256) {
        int idx, M;
        if (i < 512)      { idx = i;       M = 2048; }
        else if (i < 640) { idx = i - 512; M = 512; }
        else if (i < 672) { idx = i - 640; M = 128; }
        else              { idx = i - 672; M = 32; }
        float sn, cs;
        __sincosf(-6.28318530717958647692f * (float)idx / (float)M, &sn, &cs);
        tw[i] = make_float2(cs, sn);
    }

    // round-A loads (channels grp*8 + 0..3)
    float4 qa[8], ka[8];
    #pragma unroll
    for (int u = 0; u < 8; ++u) {
        const size_t r = base + (size_t)(tid + 256 * u) * ND;
        qa[u] = *(const float4*)(q + r);
        ka[u] = *(const float4*)(k + r);
    }
    #pragma unroll
    for (int u = 0; u < 8; ++u) {
        const int t = tid + 256 * u;
        #pragma unroll
        for (int c = 0; c < 4; ++c)
            z[c][SW2(t)] = make_float2((&qa[u].x)[c], (&ka[u].x)[c]);
    }
    // round-B loads issued now, consumed after round A (latency hidden)
    float4 qb[8], kb[8];
    #pragma unroll
    for (int u = 0; u < 8; ++u) {
        const size_t r = base + (size_t)(tid + 256 * u) * ND + 4;
        qb[u] = *(const float4*)(q + r);
        kb[u] = *(const float4*)(k + r);
    }

    float accR[8], accI[8];
    #pragma unroll
    for (int u = 0; u < 8; ++u) { accR[u] = 0.f; accI[u] = 0.f; }

    const int lane = tid & 63;
    const int wch  = tid >> 6;          // wave -> channel
    const float RH = 0.70710678118654752440f;

    for (int round = 0; round < 2; ++round) {
        __syncthreads();                // covers LDS staging (+tables, round 0)

        // ---- 4 radix-4 DIF stages: M = 2048, 512, 128, 32 ----
        const int tb[4] = {0, 512, 640, 672};
        #pragma unroll
        for (int st = 0; st < 4; ++st) {
            const int lq = 9 - 2 * st;
            const int qq = 1 << lq;
            const float2* twb = &tw[tb[st]];
            #pragma unroll
            for (int u = 0; u < 8; ++u) {
                const int j  = lane + (u << 6);
                const int kk = j & (qq - 1);
                const int i0 = ((j >> lq) << (lq + 2)) | kk;
                const float2 x0 = z[wch][SW2(i0)];
                const float2 x1 = z[wch][SW2(i0 + qq)];
                const float2 x2 = z[wch][SW2(i0 + 2 * qq)];
                const float2 x3 = z[wch][SW2(i0 + 3 * qq)];
                const float2 w1 = twb[kk];
                const float cs = w1.x, sn = w1.y;
                const float c2 = cs * cs - sn * sn, s2 = 2.f * cs * sn;
                const float Ar = x0.x + x2.x, Ai = x0.y + x2.y;
                const float B0r = x0.x - x2.x, B0i = x0.y - x2.y;
                const float Cr = x1.x + x3.x, Ci = x1.y + x3.y;
                const float D0r = x1.x - x3.x, D0i = x1.y - x3.y;
                z[wch][SW2(i0)] = make_float2(Ar + Cr, Ai + Ci);
                const float T1r = Ar - Cr, T1i = Ai - Ci;
                z[wch][SW2(i0 + qq)] =
                    make_float2(T1r * c2 - T1i * s2, T1r * s2 + T1i * c2);
                const float Br = B0r * cs - B0i * sn, Bi = B0r * sn + B0i * cs;
                const float Dr = D0r * sn + D0i * cs, Di = D0i * sn - D0r * cs;
                z[wch][SW2(i0 + 2 * qq)] = make_float2(Br + Dr, Bi + Di);
                const float T3r = Br - Dr, T3i = Bi - Di;
                z[wch][SW2(i0 + 3 * qq)] =
                    make_float2(T3r * c2 - T3i * s2, T3r * s2 + T3i * c2);
            }
            __syncthreads();
        }

        // ---- radix-8 tail (M=8,4,2), constant twiddles ----
        #pragma unroll
        for (int c4 = 0; c4 < 4; ++c4) {
            const int pb = tid << 3;
            float2 e[8];
            #pragma unroll
            for (int c = 0; c < 8; ++c) e[c] = z[c4][SW2(pb | c)];
            float ur[4], ui[4], vr[4], vi[4];
            ur[0] = e[0].x + e[4].x; ui[0] = e[0].y + e[4].y;
            vr[0] = e[0].x - e[4].x; vi[0] = e[0].y - e[4].y;
            { const float a = e[1].x - e[5].x, bq = e[1].y - e[5].y;
              ur[1] = e[1].x + e[5].x; ui[1] = e[1].y + e[5].y;
              vr[1] = RH * (a + bq); vi[1] = RH * (bq - a); }
            { const float a = e[2].x - e[6].x, bq = e[2].y - e[6].y;
              ur[2] = e[2].x + e[6].x; ui[2] = e[2].y + e[6].y;
              vr[2] = bq; vi[2] = -a; }
            { const float a = e[3].x - e[7].x, bq = e[3].y - e[7].y;
              ur[3] = e[3].x + e[7].x; ui[3] = e[3].y + e[7].y;
              vr[3] = RH * (bq - a); vi[3] = -RH * (a + bq); }
            {
                const float a0r = ur[0] + ur[2], a0i = ui[0] + ui[2];
                const float a2r = ur[0] - ur[2], a2i = ui[0] - ui[2];
                const float a1r = ur[1] + ur[3], a1i = ui[1] + ui[3];
                const float a3r = ui[1] - ui[3], a3i = -(ur[1] - ur[3]);
                z[c4][SW2(pb | 0)] = make_float2(a0r + a1r, a0i + a1i);
                z[c4][SW2(pb | 1)] = make_float2(a0r - a1r, a0i - a1i);
                z[c4][SW2(pb | 2)] = make_float2(a2r + a3r, a2i + a3i);
                z[c4][SW2(pb | 3)] = make_float2(a2r - a3r, a2i - a3i);
            }
            {
                const float a0r = vr[0] + vr[2], a0i = vi[0] + vi[2];
                const float a2r = vr[0] - vr[2], a2i = vi[0] - vi[2];
                const float a1r = vr[1] + vr[3], a1i = vi[1] + vi[3];
                const float a3r = vi[1] - vi[3], a3i = -(vr[1] - vr[3]);
                z[c4][SW2(pb | 4)] = make_float2(a0r + a1r, a0i + a1i);
                z[c4][SW2(pb | 5)] = make_float2(a0r - a1r, a0i - a1i);
                z[c4][SW2(pb | 6)] = make_float2(a2r + a3r, a2i + a3i);
                z[c4][SW2(pb | 7)] = make_float2(a2r - a3r, a2i - a3i);
            }
        }
        __syncthreads();

        // ---- product accumulate: f = fb | lane<<5 -> consecutive BR slots ----
        #pragma unroll
        for (int u = 0; u < 8; ++u) {
            const int fb = wch * 8 + u;
            const int f  = fb | (lane << 5);
            const int m  = (2048 - f) & 2047;
            const int p  = (int)(__brev((unsigned)f) >> 21);
            const int pm = (int)(__brev((unsigned)m) >> 21);
            float sr = 0.f, si = 0.f;
            #pragma unroll
            for (int c = 0; c < 4; ++c) {
                const float2 Zf = z[c][SW2(p)];
                const float2 Zm = z[c][SW2(pm)];
                const float qr = 0.5f * (Zf.x + Zm.x), qi = 0.5f * (Zf.y - Zm.y);
                const float kr = 0.5f * (Zf.y + Zm.y), ki = 0.5f * (Zm.x - Zf.x);
                sr += qr * kr + qi * ki;
                si += qi * kr - qr * ki;
            }
            accR[u] += sr; accI[u] += si;
        }

        if (round == 0) {
            __syncthreads();            // product reads done before overwrite
            #pragma unroll
            for (int u = 0; u < 8; ++u) {
                const int t = tid + 256 * u;
                #pragma unroll
                for (int c = 0; c < 4; ++c)
                    z[c][SW2(t)] = make_float2((&qb[u].x)[c], (&kb[u].x)[c]);
            }
        }
    }

    // ---- one coalesced partial store per block ----
    const int part = h * 8 + grp;       // 0..63
    float2* Pp = P + (size_t)part * (NB * 2048) + (size_t)b * 2048;
    #pragma unroll
    for (int u = 0; u < 8; ++u) {
        const int f = (wch * 8 + u) | (lane << 5);
        const int p = (int)(__brev((unsigned)f) >> 21);
        Pp[p] = make_float2(accR[u], accI[u]);
    }
}

// ---------------------------------------------------------------------------
// Reduce: S[b][pos] = sum over 64 partials. 64 blocks x 256, coalesced.
// ---------------------------------------------------------------------------
__global__ __launch_bounds__(256) void reduce_S(const float2* __restrict__ P,
                                                float2* __restrict__ S) {
    const int g = blockIdx.x * 256 + threadIdx.x;   // b*2048 + pos
    float accx = 0.f, accy = 0.f;
    #pragma unroll 8
    for (int part = 0; part < 64; ++part) {
        const float2 v = P[(size_t)part * (NB * 2048) + g];
        accx += v.x; accy += v.y;
    }
    S[g] = make_float2(accx, accy);
}

// ---------------------------------------------------------------------------
// Kernel B: block per batch, 1024 threads. S is already the DIT (bit-reversed)
// input; inverse DIT -> natural order, scale, shuffle-based top-16, softmax.
// ---------------------------------------------------------------------------
__global__ __launch_bounds__(1024) void ifft_topk(const float2* __restrict__ S,
                                                  float* __restrict__ wout,
                                                  int* __restrict__ dout) {
    const int b = blockIdx.x, tid = threadIdx.x;
    __shared__ float2 y[LSEQ];
    __shared__ float  mc[LSEQ];
    __shared__ float  pv[16];
    __shared__ int    pi[16];
    __shared__ float  topv[NDEL];
    __shared__ int    topi[NDEL];

    y[tid]        = S[b * 2048 + tid];
    y[tid + 1024] = S[b * 2048 + tid + 1024];
    __syncthreads();

    for (int M = 2; M <= LSEQ; M <<= 1) {
        const int   half = M >> 1;
        const float w0   = 6.28318530717958647692f / (float)M;
        const int   kk = tid & (half - 1), i0 = 2 * tid - kk, i1 = i0 + half;
        const float2 a = y[i0], bb = y[i1];
        float sn, cs;
        __sincosf(w0 * (float)kk, &sn, &cs);
        const float tx = bb.x * cs - bb.y * sn, ty = bb.x * sn + bb.y * cs;
        y[i0] = make_float2(a.x + tx, a.y + ty);
        y[i1] = make_float2(a.x - tx, a.y - ty);
        __syncthreads();
    }

    const float scale = 1.0f / ((float)LSEQ * (float)(NH * ND));
    mc[tid]        = y[tid].x * scale;
    mc[tid + 1024] = y[tid + 1024].x * scale;
    __syncthreads();

    const int lane = tid & 63, wv = tid >> 6;
    for (int it = 0; it < NDEL; ++it) {
        const float v0 = mc[tid], v1 = mc[tid + 1024];
        float bv; int bix;
        if (v1 > v0) { bv = v1; bix = tid + 1024; } else { bv = v0; bix = tid; }
        #pragma unroll
        for (int off = 32; off; off >>= 1) {
            const float ov = __shfl_xor(bv, off);
            const int   oi = __shfl_xor(bix, off);
            if (ov > bv || (ov == bv && oi < bix)) { bv = ov; bix = oi; }
        }
        if (lane == 0) { pv[wv] = bv; pi[wv] = bix; }
        __syncthreads();
        if (tid < 64) {
            float v = (tid < 16) ? pv[tid] : -3e38f;
            int  ii = (tid < 16) ? pi[tid] : 0;
            #pragma unroll
            for (int off = 8; off; off >>= 1) {
                const float ov = __shfl_xor(v, off);
                const int   oi = __shfl_xor(ii, off);
                if (ov > v || (ov == v && oi < ii)) { v = ov; ii = oi; }
            }
            if (tid == 0) { topv[it] = v; topi[it] = ii; mc[ii] = -3e38f; }
        }
        __syncthreads();
    }

    if (tid == 0) {
        const float m = topv[0];
        float e[NDEL], sum = 0.f;
        for (int t2 = 0; t2 < NDEL; ++t2) { e[t2] = __expf(topv[t2] - m); sum += e[t2]; }
        const float inv = 1.0f / sum;
        for (int t2 = 0; t2 < NDEL; ++t2) {
            wout[b * NDEL + t2] = e[t2] * inv;
            dout[b * NDEL + t2] = topi[t2];
        }
    }
}

// ---------------------------------------------------------------------------
// Kernel C: out[b,h,t,d] = sum_k w[b,k] * v[b,h,(t+delay[b,k]) & 2047, d]
// XCD swizzle: 128 t-tiles of one (b,h) share an XCD (v slice L2-resident).
// ---------------------------------------------------------------------------
__global__ __launch_bounds__(256) void gather_out(const float* __restrict__ v,
                                                  const float* __restrict__ w,
                                                  const int* __restrict__ delay,
                                                  float* __restrict__ out) {
    const int bi  = blockIdx.x;          // 8192 = 64 bh * 128 tiles
    const int xcd = bi & 7;
    const int s   = bi >> 3;             // 0..1023
    const int bh  = xcd * 8 + (s >> 7);
    const int bt  = s & 127;
    const int b   = bh >> 3;
    const int tid = threadIdx.x;

    __shared__ float sw_[NDEL];
    __shared__ int   sd_[NDEL];
    if (tid < NDEL) {
        sw_[tid] = w[b * NDEL + tid];
        sd_[tid] = delay[b * NDEL + tid];
    }
    __syncthreads();

    const float* vb = v + (size_t)bh * LSEQ * ND;
    float*       ob = out + (size_t)bh * LSEQ * ND;

    const int row = tid >> 4;
    const int col = (tid & 15) * 4;
    const int t   = bt * 16 + row;

    float4 acc = make_float4(0.f, 0.f, 0.f, 0.f);
    #pragma unroll
    for (int kk = 0; kk < NDEL; ++kk) {
        const int r = (t + sd_[kk]) & (LSEQ - 1);
        const float4 vv = *(const float4*)(vb + (size_t)r * ND + col);
        const float wv = sw_[kk];
        acc.x += wv * vv.x; acc.y += wv * vv.y;
        acc.z += wv * vv.z; acc.w += wv * vv.w;
    }
    *(float4*)(ob + (size_t)t * ND + col) = acc;
}

// ---------------------------------------------------------------------------
extern "C" void kernel_launch(void* const* d_in, const int* in_sizes, int n_in,
                              void* d_out, int out_size, void* d_ws, size_t ws_size,
                              hipStream_t stream) {
    const float* q = (const float*)d_in[0];
    const float* k = (const float*)d_in[1];
    const float* v = (const float*)d_in[2];
    float* out = (float*)d_out;

    float2* P     = (float2*)((char*)d_ws + WS_P_OFF);
    float2* S     = (float2*)((char*)d_ws + WS_S_OFF);
    float*  w     = (float*)((char*)d_ws + WS_W_OFF);
    int*    delay = (int*)((char*)d_ws + WS_DELAY_OFF);

    fft_corr<<<dim3(512), dim3(256), 0, stream>>>(q, k, P);
    reduce_S<<<dim3(64), dim3(256), 0, stream>>>(P, S);
    ifft_topk<<<dim3(NB), dim3(1024), 0, stream>>>(S, w, delay);
    gather_out<<<dim3(NB * NH * 128), dim3(256), 0, stream>>>(v, w, delay, out);
}

// Round 5
// 226.715 us; speedup vs baseline: 1.0007x; 1.0007x over previous
//
#include <hip/hip_runtime.h>

// B=8, H=8, L=2048, D=64, num_delays=16
static constexpr int LSEQ = 2048;
static constexpr int NB   = 8;
static constexpr int NH   = 8;
static constexpr int ND   = 64;
static constexpr int NDEL = 16;

// ws layout:
//   P     : float2[64 part][8 b][2048]  at 0        (8 MiB) partial spectra, digit-rev order
//   w     : float [8][16]               at 8388608
//   delay : int   [8][16]               at 8389120
static constexpr size_t WS_P_OFF     = 0;
static constexpr size_t WS_W_OFF     = 8388608;
static constexpr size_t WS_DELAY_OFF = 8389120;

// LDS bank swizzle on float2 index: fold bits 4..6 into bits 1..3.
__device__ __forceinline__ int SWZ(int x) { return x ^ (((x >> 4) & 7) << 1); }

// digit-reversed position of frequency f (radices 8,8,8,4 DIF) and inverse
__device__ __forceinline__ int pof(int f) {
    return ((f & 7) << 8) | (((f >> 3) & 7) << 5) | (((f >> 6) & 7) << 2) | (f >> 9);
}
__device__ __forceinline__ int fofp(int p) {
    return (p >> 8) | (((p >> 5) & 7) << 3) | (((p >> 2) & 7) << 6) | ((p & 3) << 9);
}

#define CMUL(ar, ai, br, bi) make_float2((ar)*(br) - (ai)*(bi), (ar)*(bi) + (ai)*(br))

// 8-pt DIF DFT in regs; x[0..7] in, X[0..7] (natural freq order) out.
__device__ __forceinline__ void dft8(const float2 x[8], float2 X[8]) {
    const float RH = 0.70710678118654752440f;
    float2 a0 = make_float2(x[0].x + x[4].x, x[0].y + x[4].y);
    float2 a1 = make_float2(x[1].x + x[5].x, x[1].y + x[5].y);
    float2 a2 = make_float2(x[2].x + x[6].x, x[2].y + x[6].y);
    float2 a3 = make_float2(x[3].x + x[7].x, x[3].y + x[7].y);
    float2 b0 = make_float2(x[0].x - x[4].x, x[0].y - x[4].y);
    float  t1r = x[1].x - x[5].x, t1i = x[1].y - x[5].y;
    float2 b1 = make_float2(RH * (t1r + t1i), RH * (t1i - t1r));       // * w8^1
    float  t2r = x[2].x - x[6].x, t2i = x[2].y - x[6].y;
    float2 b2 = make_float2(t2i, -t2r);                                // * -i
    float  t3r = x[3].x - x[7].x, t3i = x[3].y - x[7].y;
    float2 b3 = make_float2(RH * (t3i - t3r), -RH * (t3r + t3i));      // * w8^3
    float2 c0 = make_float2(a0.x + a2.x, a0.y + a2.y);
    float2 d0 = make_float2(a0.x - a2.x, a0.y - a2.y);
    float2 c1 = make_float2(a1.x + a3.x, a1.y + a3.y);
    float2 d1 = make_float2(a1.y - a3.y, -(a1.x - a3.x));              // * -i
    X[0] = make_float2(c0.x + c1.x, c0.y + c1.y);
    X[4] = make_float2(c0.x - c1.x, c0.y - c1.y);
    X[2] = make_float2(d0.x + d1.x, d0.y + d1.y);
    X[6] = make_float2(d0.x - d1.x, d0.y - d1.y);
    float2 e0 = make_float2(b0.x + b2.x, b0.y + b2.y);
    float2 f0 = make_float2(b0.x - b2.x, b0.y - b2.y);
    float2 e1 = make_float2(b1.x + b3.x, b1.y + b3.y);
    float2 f1 = make_float2(b1.y - b3.y, -(b1.x - b3.x));              // * -i
    X[1] = make_float2(e0.x + e1.x, e0.y + e1.y);
    X[5] = make_float2(e0.x - e1.x, e0.y - e1.y);
    X[3] = make_float2(f0.x + f1.x, f0.y + f1.y);
    X[7] = make_float2(f0.x - f1.x, f0.y - f1.y);
}

// 4-pt DFT: X[m] = sum_j x[j] (-i)^{jm}
__device__ __forceinline__ void dft4(const float2 x[4], float2 X[4]) {
    float2 s0 = make_float2(x[0].x + x[2].x, x[0].y + x[2].y);
    float2 s1 = make_float2(x[1].x + x[3].x, x[1].y + x[3].y);
    float2 d0 = make_float2(x[0].x - x[2].x, x[0].y - x[2].y);
    float2 d1 = make_float2(x[1].y - x[3].y, -(x[1].x - x[3].x));      // * -i
    X[0] = make_float2(s0.x + s1.x, s0.y + s1.y);
    X[2] = make_float2(s0.x - s1.x, s0.y - s1.y);
    X[1] = make_float2(d0.x + d1.x, d0.y + d1.y);
    X[3] = make_float2(d0.x - d1.x, d0.y - d1.y);
}

// ---------------------------------------------------------------------------
// Kernel A: block = (b,h,grp of 8 d-channels). Mixed-radix 8*8*8*4 DIF FFT,
// 3 LDS round trips, register twiddle chains. Product uses
// P[2048-f] = conj(P[f]); owned slots cc in {0,1,4,5} (p&3 in {0,1} <=> f<1024).
// ---------------------------------------------------------------------------
__global__ __launch_bounds__(256, 3) void fft_corr(const float* __restrict__ q,
                                                   const float* __restrict__ k,
                                                   float2* __restrict__ P) {
    __shared__ float2 z[LSEQ];          // 16 KiB (swizzled)
    const int t   = threadIdx.x;
    const int bi  = blockIdx.x;         // 512 = 8 xcd * 8 bh * 8 grp
    const int xcd = bi & 7;
    const int sl  = bi >> 3;
    const int bh  = xcd * 8 + (sl >> 3);
    const int grp = sl & 7;
    const int b   = bh >> 3;
    const int h   = bh & 7;
    const size_t base = (size_t)bh * LSEQ * ND + (size_t)(grp * 8);

    // twiddle power chains (per thread, shared by all 8 channels)
    float2 WA[7], WB[7], WC[7];
    {
        float sn, cs;
        __sincosf(-6.28318530717958647692f * (float)t / 2048.f, &sn, &cs);
        WA[0] = make_float2(cs, sn);
        __sincosf(-6.28318530717958647692f * (float)(t & 31) / 256.f, &sn, &cs);
        WB[0] = make_float2(cs, sn);
        __sincosf(-6.28318530717958647692f * (float)(t & 3) / 32.f, &sn, &cs);
        WC[0] = make_float2(cs, sn);
        #pragma unroll
        for (int m = 1; m < 7; ++m) {
            WA[m] = CMUL(WA[m-1].x, WA[m-1].y, WA[0].x, WA[0].y);
            WB[m] = CMUL(WB[m-1].x, WB[m-1].y, WB[0].x, WB[0].y);
            WC[m] = CMUL(WC[m-1].x, WC[m-1].y, WC[0].x, WC[0].y);
        }
    }

    // owned product slots: cc in {0,1,4,5} -> f in [0,1024)
    int fS[4], pmS[4];
    #pragma unroll
    for (int s = 0; s < 4; ++s) {
        const int cc = (s < 2) ? s : s + 2;           // {0,1,4,5}  (R4 bug: was s+3)
        const int f  = fofp(8 * t + cc);
        const int m  = (2048 - f) & 2047;
        fS[s]  = f;
        pmS[s] = SWZ(pof(m));
    }
    float aFr[4] = {0, 0, 0, 0}, aFi[4] = {0, 0, 0, 0};
    float aS = 0.f;                      // f=1024 special (thread 0)

    const int sbB   = (t >> 5) * 256 + (t & 31);
    const int baseC = (t >> 2) * 32 + (t & 3);

    for (int half = 0; half < 2; ++half) {
        float4 qa[8], ka[8];
        #pragma unroll
        for (int j = 0; j < 8; ++j) {
            const size_t r = base + (size_t)(t + 256 * j) * ND + half * 4;
            qa[j] = *(const float4*)(q + r);
            ka[j] = *(const float4*)(k + r);
        }
        #pragma unroll
        for (int c = 0; c < 4; ++c) {
            float2 X[8], Y[8];
            #pragma unroll
            for (int j = 0; j < 8; ++j)
                X[j] = make_float2((&qa[j].x)[c], (&ka[j].x)[c]);

            __syncthreads();             // z free (prev channel's readers done)

            // stage A: radix-8 on rows t+256j, twiddle WA^m, scatter to bands
            dft8(X, Y);
            #pragma unroll
            for (int m = 1; m < 8; ++m) Y[m] = CMUL(Y[m].x, Y[m].y, WA[m-1].x, WA[m-1].y);
            #pragma unroll
            for (int m = 0; m < 8; ++m) z[SWZ(m * 256 + t)] = Y[m];
            __syncthreads();

            // stage B: in-place radix-8 within 256-band, twiddle WB^m
            {
                int adr[8];
                #pragma unroll
                for (int n = 0; n < 8; ++n) adr[n] = SWZ(sbB + 32 * n);
                #pragma unroll
                for (int j = 0; j < 8; ++j) X[j] = z[adr[j]];
                dft8(X, Y);
                #pragma unroll
                for (int m = 1; m < 8; ++m) Y[m] = CMUL(Y[m].x, Y[m].y, WB[m-1].x, WB[m-1].y);
                #pragma unroll
                for (int m = 0; m < 8; ++m) z[adr[m]] = Y[m];
            }
            __syncthreads();

            // stage C: in-place radix-8 within 32-band, twiddle WC^m
            {
                int adr[8];
                #pragma unroll
                for (int n = 0; n < 8; ++n) adr[n] = SWZ(baseC + 4 * n);
                #pragma unroll
                for (int j = 0; j < 8; ++j) X[j] = z[adr[j]];
                dft8(X, Y);
                #pragma unroll
                for (int m = 1; m < 8; ++m) Y[m] = CMUL(Y[m].x, Y[m].y, WC[m-1].x, WC[m-1].y);
                #pragma unroll
                for (int m = 0; m < 8; ++m) z[adr[m]] = Y[m];
            }
            __syncthreads();

            // stage D: two radix-4 (no twiddle) on 8 consecutive; keep in regs
            {
                int adr[8];
                #pragma unroll
                for (int n = 0; n < 8; ++n) adr[n] = SWZ(8 * t + n);
                float2 xin[8];
                #pragma unroll
                for (int j = 0; j < 8; ++j) xin[j] = z[adr[j]];
                dft4(&xin[0], &X[0]);
                dft4(&xin[4], &X[4]);
                #pragma unroll
                for (int m = 0; m < 8; ++m) z[adr[m]] = X[m];
            }
            __syncthreads();

            // product: P[f] += Q[f] conj(K[f]) for 4 owned slots (+f=1024)
            #pragma unroll
            for (int s = 0; s < 4; ++s) {
                const int cc = (s < 2) ? s : s + 2;   // {0,1,4,5}
                const float2 Zf = X[cc];
                const float2 Zm = z[pmS[s]];
                const float qr = 0.5f * (Zf.x + Zm.x), qi = 0.5f * (Zf.y - Zm.y);
                const float kr = 0.5f * (Zf.y + Zm.y), ki = 0.5f * (Zm.x - Zf.x);
                aFr[s] += qr * kr + qi * ki;
                aFi[s] += qi * kr - qr * ki;
            }
            if (t == 0) aS += X[2].x * X[2].y;   // f = 1024 (self-paired)
        }
    }

    // stores: direct slots contiguous; mirrors conj-scattered (disjoint slots)
    const int part = h * 8 + grp;
    float2* Pp = P + (size_t)part * (NB * 2048) + (size_t)b * 2048;
    *(float4*)&Pp[8 * t]     = make_float4(aFr[0], aFi[0], aFr[1], aFi[1]);
    *(float4*)&Pp[8 * t + 4] = make_float4(aFr[2], aFi[2], aFr[3], aFi[3]);
    #pragma unroll
    for (int s = 0; s < 4; ++s) {
        const int m = (2048 - fS[s]) & 2047;
        if (m != fS[s]) Pp[pof(m)] = make_float2(aFr[s], -aFi[s]);
    }
    if (t == 0) Pp[pof(1024)] = make_float2(aS, 0.f);
}

// ---------------------------------------------------------------------------
// Kernel B: block per batch, 1024 threads. Fused: sum 64 partials (coalesced),
// unscramble digit-rev -> radix-2 bit-rev during LDS scatter, inverse DIT,
// scale, shuffle top-16 (ties -> smaller index), softmax.
// ---------------------------------------------------------------------------
__global__ __launch_bounds__(1024) void ifft_topk(const float2* __restrict__ P,
                                                  float* __restrict__ wout,
                                                  int* __restrict__ dout) {
    const int b = blockIdx.x, tid = threadIdx.x;
    __shared__ float2 y[LSEQ];
    __shared__ float  mc[LSEQ];
    __shared__ float  pv[16];
    __shared__ int    pi[16];
    __shared__ float  topv[NDEL];
    __shared__ int    topi[NDEL];

    // reduce 64 partials
    float2 s0 = make_float2(0.f, 0.f), s1 = make_float2(0.f, 0.f);
    const float2* Pb = P + (size_t)b * 2048;
    #pragma unroll 8
    for (int part = 0; part < 64; ++part) {
        const float2 v0 = Pb[(size_t)part * (NB * 2048) + tid];
        const float2 v1 = Pb[(size_t)part * (NB * 2048) + tid + 1024];
        s0.x += v0.x; s0.y += v0.y; s1.x += v1.x; s1.y += v1.y;
    }
    y[__brev((unsigned)fofp(tid)) >> 21]        = s0;
    y[__brev((unsigned)fofp(tid + 1024)) >> 21] = s1;
    __syncthreads();

    for (int M = 2; M <= LSEQ; M <<= 1) {
        const int   half = M >> 1;
        const float w0   = 6.28318530717958647692f / (float)M;
        const int   kk = tid & (half - 1), i0 = 2 * tid - kk, i1 = i0 + half;
        const float2 a = y[i0], bb = y[i1];
        float sn, cs;
        __sincosf(w0 * (float)kk, &sn, &cs);
        const float tx = bb.x * cs - bb.y * sn, ty = bb.x * sn + bb.y * cs;
        y[i0] = make_float2(a.x + tx, a.y + ty);
        y[i1] = make_float2(a.x - tx, a.y - ty);
        __syncthreads();
    }

    const float scale = 1.0f / ((float)LSEQ * (float)(NH * ND));
    mc[tid]        = y[tid].x * scale;
    mc[tid + 1024] = y[tid + 1024].x * scale;
    __syncthreads();

    const int lane = tid & 63, wv = tid >> 6;
    for (int it = 0; it < NDEL; ++it) {
        const float v0 = mc[tid], v1 = mc[tid + 1024];
        float bv; int bix;
        if (v1 > v0) { bv = v1; bix = tid + 1024; } else { bv = v0; bix = tid; }
        #pragma unroll
        for (int off = 32; off; off >>= 1) {
            const float ov = __shfl_xor(bv, off);
            const int   oi = __shfl_xor(bix, off);
            if (ov > bv || (ov == bv && oi < bix)) { bv = ov; bix = oi; }
        }
        if (lane == 0) { pv[wv] = bv; pi[wv] = bix; }
        __syncthreads();
        if (tid < 64) {
            float v = (tid < 16) ? pv[tid] : -3e38f;
            int  ii = (tid < 16) ? pi[tid] : 0;
            #pragma unroll
            for (int off = 8; off; off >>= 1) {
                const float ov = __shfl_xor(v, off);
                const int   oi = __shfl_xor(ii, off);
                if (ov > v || (ov == v && oi < ii)) { v = ov; ii = oi; }
            }
            if (tid == 0) { topv[it] = v; topi[it] = ii; mc[ii] = -3e38f; }
        }
        __syncthreads();
    }

    if (tid == 0) {
        const float m = topv[0];
        float e[NDEL], sum = 0.f;
        for (int t2 = 0; t2 < NDEL; ++t2) { e[t2] = __expf(topv[t2] - m); sum += e[t2]; }
        const float inv = 1.0f / sum;
        for (int t2 = 0; t2 < NDEL; ++t2) {
            wout[b * NDEL + t2] = e[t2] * inv;
            dout[b * NDEL + t2] = topi[t2];
        }
    }
}

// ---------------------------------------------------------------------------
// Kernel C: out[b,h,t,d] = sum_k w[b,k] * v[b,h,(t+delay[b,k]) & 2047, d]
// XCD swizzle: 128 t-tiles of one (b,h) share an XCD (v slice L2-resident).
// ---------------------------------------------------------------------------
__global__ __launch_bounds__(256) void gather_out(const float* __restrict__ v,
                                                  const float* __restrict__ w,
                                                  const int* __restrict__ delay,
                                                  float* __restrict__ out) {
    const int bi  = blockIdx.x;          // 8192 = 64 bh * 128 tiles
    const int xcd = bi & 7;
    const int s   = bi >> 3;
    const int bh  = xcd * 8 + (s >> 7);
    const int bt  = s & 127;
    const int b   = bh >> 3;
    const int tid = threadIdx.x;

    __shared__ float sw_[NDEL];
    __shared__ int   sd_[NDEL];
    if (tid < NDEL) {
        sw_[tid] = w[b * NDEL + tid];
        sd_[tid] = delay[b * NDEL + tid];
    }
    __syncthreads();

    const float* vb = v + (size_t)bh * LSEQ * ND;
    float*       ob = out + (size_t)bh * LSEQ * ND;

    const int row = tid >> 4;
    const int col = (tid & 15) * 4;
    const int t   = bt * 16 + row;

    float4 acc = make_float4(0.f, 0.f, 0.f, 0.f);
    #pragma unroll
    for (int kk = 0; kk < NDEL; ++kk) {
        const int r = (t + sd_[kk]) & (LSEQ - 1);
        const float4 vv = *(const float4*)(vb + (size_t)r * ND + col);
        const float wv = sw_[kk];
        acc.x += wv * vv.x; acc.y += wv * vv.y;
        acc.z += wv * vv.z; acc.w += wv * vv.w;
    }
    *(float4*)(ob + (size_t)t * ND + col) = acc;
}

// ---------------------------------------------------------------------------
extern "C" void kernel_launch(void* const* d_in, const int* in_sizes, int n_in,
                              void* d_out, int out_size, void* d_ws, size_t ws_size,
                              hipStream_t stream) {
    const float* q = (const float*)d_in[0];
    const float* k = (const float*)d_in[1];
    const float* v = (const float*)d_in[2];
    float* out = (float*)d_out;

    float2* P     = (float2*)((char*)d_ws + WS_P_OFF);
    float*  w     = (float*)((char*)d_ws + WS_W_OFF);
    int*    delay = (int*)((char*)d_ws + WS_DELAY_OFF);

    fft_corr<<<dim3(512), dim3(256), 0, stream>>>(q, k, P);
    ifft_topk<<<dim3(NB), dim3(1024), 0, stream>>>(P, w, delay);
    gather_out<<<dim3(NB * NH * 128), dim3(256), 0, stream>>>(v, w, delay, out);
}

// Round 6
// 200.235 us; speedup vs baseline: 1.1330x; 1.1322x over previous
//
#include <hip/hip_runtime.h>

// B=8, H=8, L=2048, D=64, num_delays=16
static constexpr int LSEQ = 2048;
static constexpr int NB   = 8;
static constexpr int NH   = 8;
static constexpr int ND   = 64;
static constexpr int NDEL = 16;

// ws layout (8.4 MiB total — proven-safe size):
//   P     : float2[64 part][8 b][2048]  at 0        (8 MiB) partial spectra, digit-rev order
//           (after reduce_S, part 0 holds the reduced spectrum S in-place)
//   w     : float [8][16]               at 8388608
//   delay : int   [8][16]               at 8389120
static constexpr size_t WS_P_OFF     = 0;
static constexpr size_t WS_W_OFF     = 8388608;
static constexpr size_t WS_DELAY_OFF = 8389120;

// LDS bank swizzle on float2 index: fold bits 4..6 into bits 1..3.
__device__ __forceinline__ int SWZ(int x) { return x ^ (((x >> 4) & 7) << 1); }

// digit-reversed position of frequency f (radices 8,8,8,4 DIF) and inverse
__device__ __forceinline__ int pof(int f) {
    return ((f & 7) << 8) | (((f >> 3) & 7) << 5) | (((f >> 6) & 7) << 2) | (f >> 9);
}
__device__ __forceinline__ int fofp(int p) {
    return (p >> 8) | (((p >> 5) & 7) << 3) | (((p >> 2) & 7) << 6) | ((p & 3) << 9);
}

#define CMUL(ar, ai, br, bi) make_float2((ar)*(br) - (ai)*(bi), (ar)*(bi) + (ai)*(br))

// 8-pt DIF DFT in regs; x[0..7] in, X[0..7] (natural freq order) out.
__device__ __forceinline__ void dft8(const float2 x[8], float2 X[8]) {
    const float RH = 0.70710678118654752440f;
    float2 a0 = make_float2(x[0].x + x[4].x, x[0].y + x[4].y);
    float2 a1 = make_float2(x[1].x + x[5].x, x[1].y + x[5].y);
    float2 a2 = make_float2(x[2].x + x[6].x, x[2].y + x[6].y);
    float2 a3 = make_float2(x[3].x + x[7].x, x[3].y + x[7].y);
    float2 b0 = make_float2(x[0].x - x[4].x, x[0].y - x[4].y);
    float  t1r = x[1].x - x[5].x, t1i = x[1].y - x[5].y;
    float2 b1 = make_float2(RH * (t1r + t1i), RH * (t1i - t1r));       // * w8^1
    float  t2r = x[2].x - x[6].x, t2i = x[2].y - x[6].y;
    float2 b2 = make_float2(t2i, -t2r);                                // * -i
    float  t3r = x[3].x - x[7].x, t3i = x[3].y - x[7].y;
    float2 b3 = make_float2(RH * (t3i - t3r), -RH * (t3r + t3i));      // * w8^3
    float2 c0 = make_float2(a0.x + a2.x, a0.y + a2.y);
    float2 d0 = make_float2(a0.x - a2.x, a0.y - a2.y);
    float2 c1 = make_float2(a1.x + a3.x, a1.y + a3.y);
    float2 d1 = make_float2(a1.y - a3.y, -(a1.x - a3.x));              // * -i
    X[0] = make_float2(c0.x + c1.x, c0.y + c1.y);
    X[4] = make_float2(c0.x - c1.x, c0.y - c1.y);
    X[2] = make_float2(d0.x + d1.x, d0.y + d1.y);
    X[6] = make_float2(d0.x - d1.x, d0.y - d1.y);
    float2 e0 = make_float2(b0.x + b2.x, b0.y + b2.y);
    float2 f0 = make_float2(b0.x - b2.x, b0.y - b2.y);
    float2 e1 = make_float2(b1.x + b3.x, b1.y + b3.y);
    float2 f1 = make_float2(b1.y - b3.y, -(b1.x - b3.x));              // * -i
    X[1] = make_float2(e0.x + e1.x, e0.y + e1.y);
    X[5] = make_float2(e0.x - e1.x, e0.y - e1.y);
    X[3] = make_float2(f0.x + f1.x, f0.y + f1.y);
    X[7] = make_float2(f0.x - f1.x, f0.y - f1.y);
}

// 4-pt DFT: X[m] = sum_j x[j] (-i)^{jm}
__device__ __forceinline__ void dft4(const float2 x[4], float2 X[4]) {
    float2 s0 = make_float2(x[0].x + x[2].x, x[0].y + x[2].y);
    float2 s1 = make_float2(x[1].x + x[3].x, x[1].y + x[3].y);
    float2 d0 = make_float2(x[0].x - x[2].x, x[0].y - x[2].y);
    float2 d1 = make_float2(x[1].y - x[3].y, -(x[1].x - x[3].x));      // * -i
    X[0] = make_float2(s0.x + s1.x, s0.y + s1.y);
    X[2] = make_float2(s0.x - s1.x, s0.y - s1.y);
    X[1] = make_float2(d0.x + d1.x, d0.y + d1.y);
    X[3] = make_float2(d0.x - d1.x, d0.y - d1.y);
}

// in-place radix-8 stage with twiddle chain W on LDS plane zp
__device__ __forceinline__ void stageR8(float2* zp, const int adr[8], const float2 W[7]) {
    float2 X[8], Y[8];
    #pragma unroll
    for (int j = 0; j < 8; ++j) X[j] = zp[adr[j]];
    dft8(X, Y);
    #pragma unroll
    for (int m = 1; m < 8; ++m) Y[m] = CMUL(Y[m].x, Y[m].y, W[m-1].x, W[m-1].y);
    #pragma unroll
    for (int m = 0; m < 8; ++m) zp[adr[m]] = Y[m];
}

// final twiddle-free stage: two radix-4 on 8 consecutive; result also in X
__device__ __forceinline__ void stageD(float2* zp, const int adr[8], float2 X[8]) {
    float2 xin[8];
    #pragma unroll
    for (int j = 0; j < 8; ++j) xin[j] = zp[adr[j]];
    dft4(&xin[0], &X[0]);
    dft4(&xin[4], &X[4]);
    #pragma unroll
    for (int m = 0; m < 8; ++m) zp[adr[m]] = X[m];
}

// ---------------------------------------------------------------------------
// Kernel A: block = (b,h,grp of 8 d-channels). Mixed-radix 8*8*8*4 DIF FFT.
// TWO channels in flight per sync phase (two 16 KiB LDS planes): halves the
// barrier count and doubles per-phase ILP. Product uses P[2048-f]=conj(P[f]);
// owned slots cc in {0,1,4,5}. No atomics; 64 partial spectra per batch.
// ---------------------------------------------------------------------------
__global__ __launch_bounds__(256, 2) void fft_corr(const float* __restrict__ q,
                                                   const float* __restrict__ k,
                                                   float2* __restrict__ P) {
    __shared__ float2 z0[LSEQ], z1[LSEQ];   // 32 KiB (swizzled)
    const int t   = threadIdx.x;
    const int bi  = blockIdx.x;             // 512 = 8 xcd * 8 bh * 8 grp
    const int xcd = bi & 7;
    const int sl  = bi >> 3;
    const int bh  = xcd * 8 + (sl >> 3);
    const int grp = sl & 7;
    const int b   = bh >> 3;
    const int h   = bh & 7;
    const size_t base = (size_t)bh * LSEQ * ND + (size_t)(grp * 8);

    // twiddle power chains (per thread, shared by all channels)
    float2 WA[7], WB[7], WC[7];
    {
        float sn, cs;
        __sincosf(-6.28318530717958647692f * (float)t / 2048.f, &sn, &cs);
        WA[0] = make_float2(cs, sn);
        __sincosf(-6.28318530717958647692f * (float)(t & 31) / 256.f, &sn, &cs);
        WB[0] = make_float2(cs, sn);
        __sincosf(-6.28318530717958647692f * (float)(t & 3) / 32.f, &sn, &cs);
        WC[0] = make_float2(cs, sn);
        #pragma unroll
        for (int m = 1; m < 7; ++m) {
            WA[m] = CMUL(WA[m-1].x, WA[m-1].y, WA[0].x, WA[0].y);
            WB[m] = CMUL(WB[m-1].x, WB[m-1].y, WB[0].x, WB[0].y);
            WC[m] = CMUL(WC[m-1].x, WC[m-1].y, WC[0].x, WC[0].y);
        }
    }

    // owned product slots: cc in {0,1,4,5} -> f in [0,1024)
    int fS[4], pmS[4];
    #pragma unroll
    for (int s = 0; s < 4; ++s) {
        const int cc = (s < 2) ? s : s + 2;           // {0,1,4,5}
        const int f  = fofp(8 * t + cc);
        const int m  = (2048 - f) & 2047;
        fS[s]  = f;
        pmS[s] = SWZ(pof(m));
    }
    float aFr[4] = {0, 0, 0, 0}, aFi[4] = {0, 0, 0, 0};
    float aS = 0.f;                      // f=1024 special (thread 0)

    const int sbB   = (t >> 5) * 256 + (t & 31);
    const int baseC = (t >> 2) * 32 + (t & 3);
    int adrB[8], adrC[8], adrD[8];
    #pragma unroll
    for (int n = 0; n < 8; ++n) {
        adrB[n] = SWZ(sbB + 32 * n);
        adrC[n] = SWZ(baseC + 4 * n);
        adrD[n] = SWZ(8 * t + n);
    }

    #pragma unroll
    for (int half = 0; half < 2; ++half) {
        float4 qa[8], ka[8];
        #pragma unroll
        for (int j = 0; j < 8; ++j) {
            const size_t r = base + (size_t)(t + 256 * j) * ND + half * 4;
            qa[j] = *(const float4*)(q + r);
            ka[j] = *(const float4*)(k + r);
        }
        #pragma unroll
        for (int pr = 0; pr < 2; ++pr) {
            const int c0 = 2 * pr, c1 = 2 * pr + 1;
            float2 X0[8], X1[8], Y0[8], Y1[8];
            #pragma unroll
            for (int j = 0; j < 8; ++j) {
                X0[j] = make_float2((&qa[j].x)[c0], (&ka[j].x)[c0]);
                X1[j] = make_float2((&qa[j].x)[c1], (&ka[j].x)[c1]);
            }
            __syncthreads();             // z planes free (prev pair's readers done)

            // stage A: radix-8 on rows t+256j (from regs), scatter to bands
            dft8(X0, Y0);
            dft8(X1, Y1);
            #pragma unroll
            for (int m = 1; m < 8; ++m) {
                Y0[m] = CMUL(Y0[m].x, Y0[m].y, WA[m-1].x, WA[m-1].y);
                Y1[m] = CMUL(Y1[m].x, Y1[m].y, WA[m-1].x, WA[m-1].y);
            }
            #pragma unroll
            for (int m = 0; m < 8; ++m) {
                const int a = SWZ(m * 256 + t);
                z0[a] = Y0[m];
                z1[a] = Y1[m];
            }
            __syncthreads();

            stageR8(z0, adrB, WB);
            stageR8(z1, adrB, WB);
            __syncthreads();

            stageR8(z0, adrC, WC);
            stageR8(z1, adrC, WC);
            __syncthreads();

            stageD(z0, adrD, X0);
            stageD(z1, adrD, X1);
            __syncthreads();

            // product: P[f] += Q[f] conj(K[f]) for 4 owned slots (+f=1024)
            #pragma unroll
            for (int s = 0; s < 4; ++s) {
                const int cc = (s < 2) ? s : s + 2;   // {0,1,4,5}
                {
                    const float2 Zf = X0[cc], Zm = z0[pmS[s]];
                    const float qr = 0.5f * (Zf.x + Zm.x), qi = 0.5f * (Zf.y - Zm.y);
                    const float kr = 0.5f * (Zf.y + Zm.y), ki = 0.5f * (Zm.x - Zf.x);
                    aFr[s] += qr * kr + qi * ki;
                    aFi[s] += qi * kr - qr * ki;
                }
                {
                    const float2 Zf = X1[cc], Zm = z1[pmS[s]];
                    const float qr = 0.5f * (Zf.x + Zm.x), qi = 0.5f * (Zf.y - Zm.y);
                    const float kr = 0.5f * (Zf.y + Zm.y), ki = 0.5f * (Zm.x - Zf.x);
                    aFr[s] += qr * kr + qi * ki;
                    aFi[s] += qi * kr - qr * ki;
                }
            }
            if (t == 0) aS += X0[2].x * X0[2].y + X1[2].x * X1[2].y;
        }
    }

    // stores: direct slots contiguous; mirrors conj-scattered (disjoint slots)
    const int part = h * 8 + grp;
    float2* Pp = P + (size_t)part * (NB * 2048) + (size_t)b * 2048;
    *(float4*)&Pp[8 * t]     = make_float4(aFr[0], aFi[0], aFr[1], aFi[1]);
    *(float4*)&Pp[8 * t + 4] = make_float4(aFr[2], aFi[2], aFr[3], aFi[3]);
    #pragma unroll
    for (int s = 0; s < 4; ++s) {
        const int m = (2048 - fS[s]) & 2047;
        if (m != fS[s]) Pp[pof(m)] = make_float2(aFr[s], -aFi[s]);
    }
    if (t == 0) Pp[pof(1024)] = make_float2(aS, 0.f);
}

// ---------------------------------------------------------------------------
// Reduce 64 partials IN-PLACE into part 0 (thread g owns column g — race-free).
// 64 blocks x 256 spreads the 8 MiB read over many CUs.
// ---------------------------------------------------------------------------
__global__ __launch_bounds__(256) void reduce_S(float2* __restrict__ P) {
    const int g = blockIdx.x * 256 + threadIdx.x;    // 0..16383 = b*2048+pos
    float ax = 0.f, ay = 0.f;
    #pragma unroll 8
    for (int part = 0; part < 64; ++part) {
        const float2 v = P[(size_t)part * (NB * 2048) + g];
        ax += v.x; ay += v.y;
    }
    P[g] = make_float2(ax, ay);
}

// ---------------------------------------------------------------------------
// Kernel B: block per batch, 256 threads. Inverse FFT via conj trick on the
// SAME verified mixed-radix pipeline: irfft(S)[tau] = Re(FFT_fwd(conj(S))[tau])/N.
// Gather conj(S) from digit-rev slots into stage-A registers, 3 LDS round
// trips, scatter mc to natural tau, then 16-iter argmax top-k + softmax.
// ---------------------------------------------------------------------------
__global__ __launch_bounds__(256) void ifft_topk(const float2* __restrict__ S,
                                                 float* __restrict__ wout,
                                                 int* __restrict__ dout) {
    __shared__ float2 zz[LSEQ];          // 16 KiB work (swizzled in stages)
    __shared__ float  mc[LSEQ];          // 8 KiB, natural tau order
    __shared__ float  pv[4];
    __shared__ int    pig[4];
    __shared__ float  topv[NDEL];
    __shared__ int    topi[NDEL];
    const int b = blockIdx.x, t = threadIdx.x;

    float2 WA[7], WB[7], WC[7];
    {
        float sn, cs;
        __sincosf(-6.28318530717958647692f * (float)t / 2048.f, &sn, &cs);
        WA[0] = make_float2(cs, sn);
        __sincosf(-6.28318530717958647692f * (float)(t & 31) / 256.f, &sn, &cs);
        WB[0] = make_float2(cs, sn);
        __sincosf(-6.28318530717958647692f * (float)(t & 3) / 32.f, &sn, &cs);
        WC[0] = make_float2(cs, sn);
        #pragma unroll
        for (int m = 1; m < 7; ++m) {
            WA[m] = CMUL(WA[m-1].x, WA[m-1].y, WA[0].x, WA[0].y);
            WB[m] = CMUL(WB[m-1].x, WB[m-1].y, WB[0].x, WB[0].y);
            WC[m] = CMUL(WC[m-1].x, WC[m-1].y, WC[0].x, WC[0].y);
        }
    }
    const int sbB   = (t >> 5) * 256 + (t & 31);
    const int baseC = (t >> 2) * 32 + (t & 3);
    int adrB[8], adrC[8], adrD[8];
    #pragma unroll
    for (int n = 0; n < 8; ++n) {
        adrB[n] = SWZ(sbB + 32 * n);
        adrC[n] = SWZ(baseC + 4 * n);
        adrD[n] = SWZ(8 * t + n);
    }

    // coalesced load of S (digit-rev slots) into zz (non-swizzled slots)
    #pragma unroll
    for (int j = 0; j < 8; ++j) zz[t + 256 * j] = S[b * 2048 + t + 256 * j];
    __syncthreads();

    // gather stage-A operands: x[f] = conj(S[f]) at slot pof(f), f = t+256j
    float2 X[8], Y[8];
    #pragma unroll
    for (int j = 0; j < 8; ++j) {
        const float2 s = zz[pof(t + 256 * j)];
        X[j] = make_float2(s.x, -s.y);
    }
    __syncthreads();                     // all gathers done before scatter

    dft8(X, Y);
    #pragma unroll
    for (int m = 1; m < 8; ++m) Y[m] = CMUL(Y[m].x, Y[m].y, WA[m-1].x, WA[m-1].y);
    #pragma unroll
    for (int m = 0; m < 8; ++m) zz[SWZ(m * 256 + t)] = Y[m];
    __syncthreads();

    stageR8(zz, adrB, WB);
    __syncthreads();
    stageR8(zz, adrC, WC);
    __syncthreads();

    // stage D in regs only (no writeback needed)
    {
        float2 xin[8];
        #pragma unroll
        for (int j = 0; j < 8; ++j) xin[j] = zz[adrD[j]];
        dft4(&xin[0], &X[0]);
        dft4(&xin[4], &X[4]);
    }

    // mc[tau] = Re(out)/(L*H*D); slot 8t+cc holds tau = fofp(8t+cc)
    const float scale = 1.0f / ((float)LSEQ * (float)(NH * ND));
    #pragma unroll
    for (int cc = 0; cc < 8; ++cc) mc[fofp(8 * t + cc)] = X[cc].x * scale;
    __syncthreads();

    // top-16 by iterative argmax (ties -> smaller tau)
    const int lane = t & 63, wv = t >> 6;
    for (int it = 0; it < NDEL; ++it) {
        float bv = -3e38f; int bix = 0;
        #pragma unroll
        for (int u = 0; u < 8; ++u) {
            const int idx = t + 256 * u;
            const float v = mc[idx];
            if (v > bv || (v == bv && idx < bix)) { bv = v; bix = idx; }
        }
        #pragma unroll
        for (int off = 32; off; off >>= 1) {
            const float ov = __shfl_xor(bv, off);
            const int   oi = __shfl_xor(bix, off);
            if (ov > bv || (ov == bv && oi < bix)) { bv = ov; bix = oi; }
        }
        if (lane == 0) { pv[wv] = bv; pig[wv] = bix; }
        __syncthreads();
        if (t < 64) {
            float v = (t < 4) ? pv[t] : -3e38f;
            int  ii = (t < 4) ? pig[t] : 0;
            #pragma unroll
            for (int off = 2; off; off >>= 1) {
                const float ov = __shfl_xor(v, off);
                const int   oi = __shfl_xor(ii, off);
                if (ov > v || (ov == v && oi < ii)) { v = ov; ii = oi; }
            }
            if (t == 0) { topv[it] = v; topi[it] = ii; mc[ii] = -3e38f; }
        }
        __syncthreads();
    }

    if (t == 0) {
        const float m = topv[0];
        float e[NDEL], sum = 0.f;
        for (int i = 0; i < NDEL; ++i) { e[i] = __expf(topv[i] - m); sum += e[i]; }
        const float inv = 1.0f / sum;
        for (int i = 0; i < NDEL; ++i) {
            wout[b * NDEL + i] = e[i] * inv;
            dout[b * NDEL + i] = topi[i];
        }
    }
}

// ---------------------------------------------------------------------------
// Kernel C: out[b,h,t,d] = sum_k w[b,k] * v[b,h,(t+delay[b,k]) & 2047, d]
// XCD swizzle: 128 t-tiles of one (b,h) share an XCD (v slice L2-resident).
// ---------------------------------------------------------------------------
__global__ __launch_bounds__(256) void gather_out(const float* __restrict__ v,
                                                  const float* __restrict__ w,
                                                  const int* __restrict__ delay,
                                                  float* __restrict__ out) {
    const int bi  = blockIdx.x;          // 8192 = 64 bh * 128 tiles
    const int xcd = bi & 7;
    const int s   = bi >> 3;
    const int bh  = xcd * 8 + (s >> 7);
    const int bt  = s & 127;
    const int b   = bh >> 3;
    const int tid = threadIdx.x;

    __shared__ float sw_[NDEL];
    __shared__ int   sd_[NDEL];
    if (tid < NDEL) {
        sw_[tid] = w[b * NDEL + tid];
        sd_[tid] = delay[b * NDEL + tid];
    }
    __syncthreads();

    const float* vb = v + (size_t)bh * LSEQ * ND;
    float*       ob = out + (size_t)bh * LSEQ * ND;

    const int row = tid >> 4;
    const int col = (tid & 15) * 4;
    const int t   = bt * 16 + row;

    float4 acc = make_float4(0.f, 0.f, 0.f, 0.f);
    #pragma unroll
    for (int kk = 0; kk < NDEL; ++kk) {
        const int r = (t + sd_[kk]) & (LSEQ - 1);
        const float4 vv = *(const float4*)(vb + (size_t)r * ND + col);
        const float wv = sw_[kk];
        acc.x += wv * vv.x; acc.y += wv * vv.y;
        acc.z += wv * vv.z; acc.w += wv * vv.w;
    }
    *(float4*)(ob + (size_t)t * ND + col) = acc;
}

// ---------------------------------------------------------------------------
extern "C" void kernel_launch(void* const* d_in, const int* in_sizes, int n_in,
                              void* d_out, int out_size, void* d_ws, size_t ws_size,
                              hipStream_t stream) {
    const float* q = (const float*)d_in[0];
    const float* k = (const float*)d_in[1];
    const float* v = (const float*)d_in[2];
    float* out = (float*)d_out;

    float2* P     = (float2*)((char*)d_ws + WS_P_OFF);
    float*  w     = (float*)((char*)d_ws + WS_W_OFF);
    int*    delay = (int*)((char*)d_ws + WS_DELAY_OFF);

    fft_corr<<<dim3(512), dim3(256), 0, stream>>>(q, k, P);
    reduce_S<<<dim3(64), dim3(256), 0, stream>>>(P);
    ifft_topk<<<dim3(NB), dim3(256), 0, stream>>>(P, w, delay);  // S = P[part 0]
    gather_out<<<dim3(NB * NH * 128), dim3(256), 0, stream>>>(v, w, delay, out);
}